// Round 8
// baseline (748.647 us; speedup 1.0000x reference)
//
#include <hip/hip_runtime.h>
#include <hip/hip_bf16.h>

typedef __hip_bfloat16 bf16;
typedef short short8 __attribute__((ext_vector_type(8)));
typedef float f32x4 __attribute__((ext_vector_type(4)));

#define NPB 256          // nodes per bucket (multisplit coarse radix = dst>>8)
#define MAXBUK 1024      // supports N <= 262144

__device__ __forceinline__ float bf2f_raw(unsigned short u) {
    unsigned x = ((unsigned)u) << 16; float f; __builtin_memcpy(&f, &x, 4); return f;
}
__device__ __forceinline__ unsigned short f2bf_raw(float f) {   // RNE
    unsigned u; __builtin_memcpy(&u, &f, 4);
    u += 0x7FFFu + ((u >> 16) & 1u);
    return (unsigned short)(u >> 16);
}
__device__ __forceinline__ float lo_f(unsigned u) {
    unsigned x = u << 16; float f; __builtin_memcpy(&f, &x, 4); return f;
}
__device__ __forceinline__ float hi_f(unsigned u) {
    unsigned x = u & 0xffff0000u; float f; __builtin_memcpy(&f, &x, 4); return f;
}

// ---------------- dtype sniffer: flag=1 if float arrays are f32, 0 if bf16 ----------------

__global__ __launch_bounds__(1024) void sniff_kernel(const unsigned short* __restrict__ w,
                                                     int nshorts, int* __restrict__ flag) {
    __shared__ int red[1024];
    const int t = threadIdx.x;
    int c = 0;
    for (int i = t; i < nshorts; i += 1024) {
        unsigned e = (w[i] >> 7) & 0xFFu;
        if (e >= 140u || (e >= 1u && e <= 40u)) c++;
    }
    red[t] = c;
    __syncthreads();
    for (int o = 512; o > 0; o >>= 1) {
        if (t < o) red[t] += red[t + o];
        __syncthreads();
    }
    if (t == 0) *flag = (red[0] > nshorts / 8) ? 1 : 0;
}

// ---------------- prep: biases->f32; W1/W2 -> MFMA B-fragment-linear bf16 ----------------

__global__ __launch_bounds__(256) void prep_kernel(const void* __restrict__ W1p,
                                                   const void* __restrict__ W2p,
                                                   const void* __restrict__ b1p,
                                                   const void* __restrict__ b2p,
                                                   unsigned short* __restrict__ WB1,
                                                   unsigned short* __restrict__ WB2,
                                                   float* __restrict__ b1f,
                                                   float* __restrict__ b2f,
                                                   const int* __restrict__ flag) {
    const int isf32 = *flag;
    const int t = blockIdx.x * 256 + threadIdx.x;
    const int T1 = 16384, T2 = 8192;
    if (t < T1) {
        int j = t & 7, l = (t >> 3) & 63, f = t >> 9;
        int n = f >> 2, kk = f & 3;
        int k = kk * 32 + (l >> 4) * 8 + j;
        int col = n * 16 + (l & 15);
        WB1[t] = isf32 ? f2bf_raw(((const float*)W1p)[k * 128 + col])
                       : ((const unsigned short*)W1p)[k * 128 + col];
    } else if (t < T1 + T2) {
        int o = t - T1;
        int j = o & 7, l = (o >> 3) & 63, f = o >> 9;
        int n = f >> 2, kk = f & 3;
        int k = kk * 32 + (l >> 4) * 8 + j;
        int col = n * 16 + (l & 15);
        WB2[o] = isf32 ? f2bf_raw(((const float*)W2p)[k * 64 + col])
                       : ((const unsigned short*)W2p)[k * 64 + col];
    } else if (t < T1 + T2 + 128) {
        int o = t - T1 - T2;
        b1f[o] = isf32 ? ((const float*)b1p)[o] : bf2f_raw(((const unsigned short*)b1p)[o]);
    } else if (t < T1 + T2 + 192) {
        int o = t - T1 - T2 - 128;
        b2f[o] = isf32 ? ((const float*)b2p)[o] : bf2f_raw(((const unsigned short*)b2p)[o]);
    }
}

// ---------------- CSR build: count + 3-phase scan ----------------

__global__ void count_kernel(const int* __restrict__ dst, int* __restrict__ cnt, int E) {
    int e = blockIdx.x * blockDim.x + threadIdx.x;
    if (e < E) atomicAdd(&cnt[dst[e]], 1);
}

__global__ __launch_bounds__(256) void scanA_kernel(const int* __restrict__ cnt,
                                                    int* __restrict__ partial, int n) {
    __shared__ int red[256];
    const int t = threadIdx.x;
    const int base = blockIdx.x << 10;
    int s = 0;
    #pragma unroll
    for (int k = 0; k < 4; ++k) {
        int i = base + t + (k << 8);
        if (i < n) s += cnt[i];
    }
    red[t] = s;
    __syncthreads();
    for (int o = 128; o > 0; o >>= 1) {
        if (t < o) red[t] += red[t + o];
        __syncthreads();
    }
    if (t == 0) partial[blockIdx.x] = red[0];
}

__global__ __launch_bounds__(1024) void scanB_kernel(const int* __restrict__ partial,
                                                     int* __restrict__ bofs,
                                                     int* __restrict__ rofs,
                                                     int nb, int n, int total) {
    __shared__ int ps[1024];
    const int t = threadIdx.x;
    int v = (t < nb) ? partial[t] : 0;
    ps[t] = v;
    __syncthreads();
    for (int o = 1; o < 1024; o <<= 1) {
        int u = (t >= o) ? ps[t - o] : 0;
        __syncthreads();
        ps[t] += u;
        __syncthreads();
    }
    if (t < nb) bofs[t] = ps[t] - v;
    if (t == 0) rofs[n] = total;
}

__global__ __launch_bounds__(256) void scanC_kernel(const int* __restrict__ cnt,
                                                    const int* __restrict__ bofs,
                                                    int* __restrict__ rofs,
                                                    float* __restrict__ dinv, int n) {
    __shared__ int v[1024];
    __shared__ int ps[256];
    const int t = threadIdx.x;
    const int base = blockIdx.x << 10;
    #pragma unroll
    for (int k = 0; k < 4; ++k) {
        int i = base + t + (k << 8);
        v[t + (k << 8)] = (i < n) ? cnt[i] : 0;
    }
    __syncthreads();
    int a0 = v[4 * t], a1 = v[4 * t + 1], a2 = v[4 * t + 2], a3 = v[4 * t + 3];
    int s = a0 + a1 + a2 + a3;
    ps[t] = s;
    __syncthreads();
    for (int o = 1; o < 256; o <<= 1) {
        int u = (t >= o) ? ps[t - o] : 0;
        __syncthreads();
        ps[t] += u;
        __syncthreads();
    }
    int run = bofs[blockIdx.x] + ps[t] - s;
    const int idx = base + 4 * t;
    int r0 = run, r1 = run + a0, r2 = r1 + a1, r3 = r2 + a2;
    if (idx + 3 < n) {
        *reinterpret_cast<int4*>(rofs + idx) = make_int4(r0, r1, r2, r3);
        *reinterpret_cast<float4*>(dinv + idx) =
            make_float4(rsqrtf((float)(a0 + 1)), rsqrtf((float)(a1 + 1)),
                        rsqrtf((float)(a2 + 1)), rsqrtf((float)(a3 + 1)));
    } else if (idx < n) {
        int rr[4] = {r0, r1, r2, r3};
        int aa[4] = {a0, a1, a2, a3};
        for (int k = 0; k < 4 && idx + k < n; ++k) {
            rofs[idx + k] = rr[k];
            dinv[idx + k] = rsqrtf((float)(aa[k] + 1));
        }
    }
}

__global__ void bucket_init_kernel(const int* __restrict__ rofs, int* __restrict__ bcur,
                                   int nbuk) {
    int b = blockIdx.x * blockDim.x + threadIdx.x;
    if (b < nbuk) bcur[b] = rofs[b * NPB];
}

// ---------------- Phase 1: coarse multisplit of edges by dst>>8 ----------------

__global__ __launch_bounds__(256) void multisplit_kernel(const int* __restrict__ src,
                                                         const int* __restrict__ dst,
                                                         int* __restrict__ bcur,
                                                         unsigned* __restrict__ packed,
                                                         int E, int nbuk) {
    __shared__ int cnt[MAXBUK];
    __shared__ int gbase[MAXBUK];
    const int t = threadIdx.x;
    const int e0 = blockIdx.x * 8192;
    const int e1 = min(E, e0 + 8192);
    for (int b = t; b < nbuk; b += 256) cnt[b] = 0;
    __syncthreads();
    for (int e = e0 + t; e < e1; e += 256) atomicAdd(&cnt[dst[e] >> 8], 1);
    __syncthreads();
    for (int b = t; b < nbuk; b += 256) {
        int c = cnt[b];
        gbase[b] = c ? atomicAdd(&bcur[b], c) : 0;
        cnt[b] = 0;
    }
    __syncthreads();
    for (int e = e0 + t; e < e1; e += 256) {
        int d = dst[e];
        int b = d >> 8;
        int r = atomicAdd(&cnt[b], 1);
        packed[gbase[b] + r] = ((unsigned)(d & 255) << 24) | (unsigned)src[e];
    }
}

// ---------------- Phase 2: fine CSR placement, one block per bucket ----------------

__global__ __launch_bounds__(256) void csr_fine_kernel(const unsigned* __restrict__ packed,
                                                       const int* __restrict__ rofs,
                                                       int* __restrict__ csrc, int n) {
    __shared__ int cur[NPB];
    const int t = threadIdx.x;
    const int node0 = blockIdx.x << 8;
    const int nn = min(NPB, n - node0);
    if (t < nn) cur[t] = rofs[node0 + t];
    __syncthreads();
    const int beg = rofs[node0];
    const int end = rofs[node0 + nn];
    for (int i = beg + t; i < end; i += 256) {
        unsigned u = packed[i];
        int pos = atomicAdd(&cur[u >> 24], 1);
        csrc[pos] = (int)(u & 0xFFFFFFu);
    }
}

// ---------------- GEMM1 (MFMA): panels PH[s][node][16 feats] = X * W1 ----------------

template <int IS_F32>
__global__ __launch_bounds__(256) void gemm1_mfma(const void* __restrict__ Xp,
                                                  const unsigned short* __restrict__ WB1,
                                                  unsigned* __restrict__ PH, int nrows,
                                                  const int* __restrict__ flag) {
    if (*flag != IS_F32) return;
    __shared__ __align__(16) unsigned short Xs[128 * 136];
    __shared__ __align__(16) unsigned short Cs[128 * 68];
    const int t = threadIdx.x;
    const int r0 = blockIdx.x * 128;

    if (IS_F32) {
        const float4* Xg = (const float4*)Xp;
        #pragma unroll
        for (int i = 0; i < 16; ++i) {
            int idx = t + 256 * i;
            int row = idx >> 5, c4 = idx & 31;
            float4 v = {0.f, 0.f, 0.f, 0.f};
            if (r0 + row < nrows) v = Xg[(size_t)(r0 + row) * 32 + c4];
            unsigned lo = (unsigned)f2bf_raw(v.x) | ((unsigned)f2bf_raw(v.y) << 16);
            unsigned hi = (unsigned)f2bf_raw(v.z) | ((unsigned)f2bf_raw(v.w) << 16);
            *reinterpret_cast<uint2*>(&Xs[row * 136 + c4 * 4]) = make_uint2(lo, hi);
        }
    } else {
        const uint4* Xg = (const uint4*)Xp;
        #pragma unroll
        for (int i = 0; i < 8; ++i) {
            int idx = t + 256 * i;
            int row = idx >> 4, c8 = idx & 15;
            uint4 v = {0u, 0u, 0u, 0u};
            if (r0 + row < nrows) v = Xg[(size_t)(r0 + row) * 16 + c8];
            *reinterpret_cast<uint4*>(&Xs[row * 136 + c8 * 8]) = v;
        }
    }
    __syncthreads();

    const int lane = t & 63, w = t >> 6;
    const int m0 = w * 32;
    short8 a[2][4];
    #pragma unroll
    for (int rt = 0; rt < 2; ++rt)
        #pragma unroll
        for (int kk = 0; kk < 4; ++kk)
            a[rt][kk] = *reinterpret_cast<const short8*>(
                &Xs[(m0 + rt * 16 + (lane & 15)) * 136 + kk * 32 + (lane >> 4) * 8]);

    for (int p = 0; p < 2; ++p) {
        short8 b[4][4];
        #pragma unroll
        for (int n = 0; n < 4; ++n)
            #pragma unroll
            for (int kk = 0; kk < 4; ++kk)
                b[n][kk] = *reinterpret_cast<const short8*>(
                    WB1 + (size_t)(((p * 4 + n) * 4 + kk) * 64 + lane) * 8);
        f32x4 acc[2][4];
        #pragma unroll
        for (int rt = 0; rt < 2; ++rt)
            #pragma unroll
            for (int n = 0; n < 4; ++n) {
                acc[rt][n] = (f32x4){0.f, 0.f, 0.f, 0.f};
                #pragma unroll
                for (int kk = 0; kk < 4; ++kk)
                    acc[rt][n] = __builtin_amdgcn_mfma_f32_16x16x32_bf16(
                        a[rt][kk], b[n][kk], acc[rt][n], 0, 0, 0);
            }
        if (p) __syncthreads();
        #pragma unroll
        for (int rt = 0; rt < 2; ++rt)
            #pragma unroll
            for (int n = 0; n < 4; ++n)
                #pragma unroll
                for (int r = 0; r < 4; ++r) {
                    int row = m0 + rt * 16 + (lane >> 4) * 4 + r;
                    Cs[row * 68 + n * 16 + (lane & 15)] = f2bf_raw(acc[rt][n][r]);
                }
        __syncthreads();
        // copy-out: this pass covers slices p*4 .. p*4+3 (16 feats each)
        #pragma unroll
        for (int i = 0; i < 8; ++i) {
            int idx = t + 256 * i;                 // 0..2047
            int d2 = idx & 3;                      // uint2 within (slice,row)
            int row = (idx >> 2) & 127;
            int sl = idx >> 9;                     // 0..3
            if (r0 + row < nrows) {
                uint2 v = *reinterpret_cast<const uint2*>(&Cs[row * 68 + (sl * 8 + d2 * 2) * 2]);
                *reinterpret_cast<uint2*>(
                    PH + ((size_t)(p * 4 + sl) * nrows + (r0 + row)) * 8 + d2 * 2) = v;
            }
        }
        if (!p) __syncthreads();
    }
}

// ---------------- Aggregation, feature-sliced + XCD-pinned ----------------
// Panels P[s][node][8 dwords] (16 bf16 feats). slice = blockIdx%8 -> XCD round-robin;
// per-XCD working set = N*32B = 3.2 MB < 4 MB L2. 8-lane group per node.

template <bool RELU_BIAS>
__global__ __launch_bounds__(256) void agg_slice(const unsigned* __restrict__ PH,
                                                 const int* __restrict__ rofs,
                                                 const int* __restrict__ csrc,
                                                 const float* __restrict__ dinv,
                                                 const float* __restrict__ biasf,
                                                 unsigned* __restrict__ PG, int n) {
    const int s = blockIdx.x & 7;
    const int g = threadIdx.x >> 3;
    const int ln = threadIdx.x & 7;
    const int node = (blockIdx.x >> 3) * 32 + g;
    if (node >= n) return;                         // no barriers below
    const float di = dinv[node];
    const unsigned* __restrict__ P = PH + (size_t)s * n * 8;
    unsigned u = P[(size_t)node * 8 + ln];
    const float dii = di * di;
    float a0 = dii * lo_f(u), a1 = dii * hi_f(u);  // self loop
    int j = rofs[node];
    const int end = rofs[node + 1];
    for (; j + 1 < end; j += 2) {
        int s0 = __builtin_nontemporal_load(&csrc[j]);
        int s1 = __builtin_nontemporal_load(&csrc[j + 1]);
        float w0 = di * dinv[s0], w1 = di * dinv[s1];
        unsigned v0 = P[(size_t)s0 * 8 + ln];
        unsigned v1 = P[(size_t)s1 * 8 + ln];
        a0 = fmaf(w0, lo_f(v0), a0); a1 = fmaf(w0, hi_f(v0), a1);
        a0 = fmaf(w1, lo_f(v1), a0); a1 = fmaf(w1, hi_f(v1), a1);
    }
    if (j < end) {
        int s0 = __builtin_nontemporal_load(&csrc[j]);
        float w = di * dinv[s0];
        unsigned v = P[(size_t)s0 * 8 + ln];
        a0 = fmaf(w, lo_f(v), a0);
        a1 = fmaf(w, hi_f(v), a1);
    }
    if (RELU_BIAS) {
        a0 = fmaxf(a0 + biasf[s * 16 + 2 * ln], 0.f);
        a1 = fmaxf(a1 + biasf[s * 16 + 2 * ln + 1], 0.f);
    }
    PG[(size_t)s * n * 8 + (size_t)node * 8 + ln] =
        (unsigned)f2bf_raw(a0) | ((unsigned)f2bf_raw(a1) << 16);
}

// ---------------- GEMM2 (MFMA) + bias + log_softmax (A staged from panels) ----------------

template <int OUT_F32>
__global__ __launch_bounds__(256) void gemm2_mfma(const unsigned* __restrict__ PA,
                                                  const unsigned short* __restrict__ WB2,
                                                  const float* __restrict__ b2f,
                                                  void* __restrict__ OUTv, int nrows,
                                                  const int* __restrict__ flag) {
    if (*flag != OUT_F32) return;
    __shared__ __align__(16) unsigned short Xs[128 * 136];
    const int t = threadIdx.x;
    const int r0 = blockIdx.x * 128;

    #pragma unroll
    for (int i = 0; i < 8; ++i) {
        int idx = t + 256 * i;                 // 128 rows x 16 (slice,half)
        int row = idx & 127;
        int sh = idx >> 7;                     // 0..15
        int s = sh >> 1, half = sh & 1;
        uint4 v = {0u, 0u, 0u, 0u};
        if (r0 + row < nrows)
            v = *reinterpret_cast<const uint4*>(
                PA + ((size_t)s * nrows + (r0 + row)) * 8 + half * 4);
        *reinterpret_cast<uint4*>(&Xs[row * 136 + s * 16 + half * 8]) = v;
    }
    __syncthreads();

    const int lane = t & 63, w = t >> 6;
    const int m0 = w * 32;
    short8 a[2][4];
    #pragma unroll
    for (int rt = 0; rt < 2; ++rt)
        #pragma unroll
        for (int kk = 0; kk < 4; ++kk)
            a[rt][kk] = *reinterpret_cast<const short8*>(
                &Xs[(m0 + rt * 16 + (lane & 15)) * 136 + kk * 32 + (lane >> 4) * 8]);

    short8 b[4][4];
    #pragma unroll
    for (int n = 0; n < 4; ++n)
        #pragma unroll
        for (int kk = 0; kk < 4; ++kk)
            b[n][kk] = *reinterpret_cast<const short8*>(
                WB2 + (size_t)((n * 4 + kk) * 64 + lane) * 8);

    f32x4 acc[2][4];
    #pragma unroll
    for (int rt = 0; rt < 2; ++rt)
        #pragma unroll
        for (int n = 0; n < 4; ++n) {
            acc[rt][n] = (f32x4){0.f, 0.f, 0.f, 0.f};
            #pragma unroll
            for (int kk = 0; kk < 4; ++kk)
                acc[rt][n] = __builtin_amdgcn_mfma_f32_16x16x32_bf16(
                    a[rt][kk], b[n][kk], acc[rt][n], 0, 0, 0);
        }

    float bc[4];
    #pragma unroll
    for (int n = 0; n < 4; ++n) bc[n] = b2f[n * 16 + (lane & 15)];
    #pragma unroll
    for (int rt = 0; rt < 2; ++rt)
        #pragma unroll
        for (int n = 0; n < 4; ++n)
            #pragma unroll
            for (int r = 0; r < 4; ++r) acc[rt][n][r] += bc[n];

    float lse[2][4];
    #pragma unroll
    for (int rt = 0; rt < 2; ++rt)
        #pragma unroll
        for (int r = 0; r < 4; ++r) {
            float m = fmaxf(fmaxf(acc[rt][0][r], acc[rt][1][r]),
                            fmaxf(acc[rt][2][r], acc[rt][3][r]));
            #pragma unroll
            for (int o = 1; o < 16; o <<= 1) m = fmaxf(m, __shfl_xor(m, o, 64));
            float s = __expf(acc[rt][0][r] - m) + __expf(acc[rt][1][r] - m) +
                      __expf(acc[rt][2][r] - m) + __expf(acc[rt][3][r] - m);
            #pragma unroll
            for (int o = 1; o < 16; o <<= 1) s += __shfl_xor(s, o, 64);
            lse[rt][r] = m + __logf(s);
        }

    const int colb = lane & 15, q = lane >> 4;
    #pragma unroll
    for (int rt = 0; rt < 2; ++rt)
        #pragma unroll
        for (int r = 0; r < 4; ++r) {
            int grow = r0 + m0 + rt * 16 + q * 4 + r;
            if (grow < nrows) {
                if (OUT_F32) {
                    float* Of = (float*)OUTv;
                    #pragma unroll
                    for (int n = 0; n < 4; ++n)
                        Of[(size_t)grow * 64 + n * 16 + colb] = acc[rt][n][r] - lse[rt][r];
                } else {
                    unsigned short* Ob = (unsigned short*)OUTv;
                    #pragma unroll
                    for (int n = 0; n < 4; ++n)
                        Ob[(size_t)grow * 64 + n * 16 + colb] = f2bf_raw(acc[rt][n][r] - lse[rt][r]);
                }
            }
        }
}

// ---------------- launch ----------------

extern "C" void kernel_launch(void* const* d_in, const int* in_sizes, int n_in,
                              void* d_out, int out_size, void* d_ws, size_t ws_size,
                              hipStream_t stream) {
    const void* x  = d_in[0];
    const int*  ei = (const int*)d_in[1];
    const void* W1 = d_in[2];
    const void* b1 = d_in[3];
    const void* W2 = d_in[4];
    const void* b2 = d_in[5];

    const int N = in_sizes[0] / 128;
    const int E = in_sizes[1] / 2;
    const int* src = ei;
    const int* dst = ei + E;
    const int NB = (N + 1023) >> 10;
    const int NBUK = (N + NPB - 1) / NPB;

    char* p = (char*)d_ws;
    auto alloc = [&](size_t bytes) { char* q = p; p += (bytes + 255) & ~255ull; return q; };
    int*   flag    = (int*)  alloc(4);
    int*   cnt     = (int*)  alloc((size_t)N * 4);
    int*   rofs    = (int*)  alloc((size_t)(N + 1) * 4);
    float* dinv    = (float*)alloc((size_t)N * 4);
    int*   partial = (int*)  alloc((size_t)NB * 4);
    int*   bofs    = (int*)  alloc((size_t)NB * 4);
    int*   bcur    = (int*)  alloc((size_t)NBUK * 4);
    float* b1f     = (float*)alloc(128 * 4);
    float* b2f     = (float*)alloc(64 * 4);
    unsigned short* WB1 = (unsigned short*)alloc(16384 * 2);
    unsigned short* WB2 = (unsigned short*)alloc(8192 * 2);
    unsigned* big  = (unsigned*)alloc((size_t)N * 128 * 2);   // h1 panels, later a2 panels
    unsigned* packed = (unsigned*)d_out;          // 6.4 MB scratch in d_out
    int*      csrc   = (int*)d_out + E;           // 6.4 MB scratch in d_out
    unsigned* g1 = (unsigned*)d_in[0];            // g1 panels into x's buffer (x dead)
    (void)ws_size; (void)n_in; (void)out_size;

    hipMemsetAsync(cnt, 0, (size_t)N * 4, stream);
    sniff_kernel<<<1, 1024, 0, stream>>>((const unsigned short*)W1, in_sizes[2], flag);
    prep_kernel<<<97, 256, 0, stream>>>(W1, W2, b1, b2, WB1, WB2, b1f, b2f, flag);
    count_kernel<<<(E + 255) / 256, 256, 0, stream>>>(dst, cnt, E);
    scanA_kernel<<<NB, 256, 0, stream>>>(cnt, partial, N);
    scanB_kernel<<<1, 1024, 0, stream>>>(partial, bofs, rofs, NB, N, E);
    scanC_kernel<<<NB, 256, 0, stream>>>(cnt, bofs, rofs, dinv, N);
    bucket_init_kernel<<<(NBUK + 255) / 256, 256, 0, stream>>>(rofs, bcur, NBUK);
    multisplit_kernel<<<(E + 8191) / 8192, 256, 0, stream>>>(src, dst, bcur, packed, E, NBUK);
    csr_fine_kernel<<<NBUK, 256, 0, stream>>>(packed, rofs, csrc, N);

    const int GB = (N + 127) / 128;
    const int AGB = 8 * ((N + 31) / 32);
    gemm1_mfma<0><<<GB, 256, 0, stream>>>(x, WB1, big, N, flag);
    gemm1_mfma<1><<<GB, 256, 0, stream>>>(x, WB1, big, N, flag);
    agg_slice<true><<<AGB, 256, 0, stream>>>(big, rofs, csrc, dinv, b1f, g1, N);
    agg_slice<false><<<AGB, 256, 0, stream>>>(g1, rofs, csrc, dinv, nullptr, big, N);
    gemm2_mfma<0><<<GB, 256, 0, stream>>>(big, WB2, b2f, d_out, N, flag);
    gemm2_mfma<1><<<GB, 256, 0, stream>>>(big, WB2, b2f, d_out, N, flag);
}

// Round 9
// 340.534 us; speedup vs baseline: 2.1985x; 2.1985x over previous
//
#include <hip/hip_runtime.h>
#include <hip/hip_bf16.h>

typedef __hip_bfloat16 bf16;
typedef short short8 __attribute__((ext_vector_type(8)));
typedef float f32x4 __attribute__((ext_vector_type(4)));

#define NPB 256          // nodes per bucket (coarse radix = dst>>8)
#define MAXBUK 1024      // supports N <= 262144

__device__ __forceinline__ float bf2f_raw(unsigned short u) {
    unsigned x = ((unsigned)u) << 16; float f; __builtin_memcpy(&f, &x, 4); return f;
}
__device__ __forceinline__ unsigned short f2bf_raw(float f) {   // RNE
    unsigned u; __builtin_memcpy(&u, &f, 4);
    u += 0x7FFFu + ((u >> 16) & 1u);
    return (unsigned short)(u >> 16);
}
__device__ __forceinline__ float lo_f(unsigned u) {
    unsigned x = u << 16; float f; __builtin_memcpy(&f, &x, 4); return f;
}
__device__ __forceinline__ float hi_f(unsigned u) {
    unsigned x = u & 0xffff0000u; float f; __builtin_memcpy(&f, &x, 4); return f;
}

// ---------------- dtype sniffer: flag=1 if float arrays are f32, 0 if bf16 ----------------

__global__ __launch_bounds__(1024) void sniff_kernel(const unsigned short* __restrict__ w,
                                                     int nshorts, int* __restrict__ flag) {
    __shared__ int red[1024];
    const int t = threadIdx.x;
    int c = 0;
    for (int i = t; i < nshorts; i += 1024) {
        unsigned e = (w[i] >> 7) & 0xFFu;
        if (e >= 140u || (e >= 1u && e <= 40u)) c++;
    }
    red[t] = c;
    __syncthreads();
    for (int o = 512; o > 0; o >>= 1) {
        if (t < o) red[t] += red[t + o];
        __syncthreads();
    }
    if (t == 0) *flag = (red[0] > nshorts / 8) ? 1 : 0;
}

// ---------------- prep: biases->f32; W1/W2 -> MFMA B-fragment-linear bf16 ----------------
// Fragment (16x16x32 bf16 B-operand): lane l holds B[k=(l>>4)*8+j][n=l&15], j=0..7.

__global__ __launch_bounds__(256) void prep_kernel(const void* __restrict__ W1p,
                                                   const void* __restrict__ W2p,
                                                   const void* __restrict__ b1p,
                                                   const void* __restrict__ b2p,
                                                   unsigned short* __restrict__ WB1,
                                                   unsigned short* __restrict__ WB2,
                                                   float* __restrict__ b1f,
                                                   float* __restrict__ b2f,
                                                   const int* __restrict__ flag) {
    const int isf32 = *flag;
    const int t = blockIdx.x * 256 + threadIdx.x;
    const int T1 = 16384, T2 = 8192;
    if (t < T1) {
        int j = t & 7, l = (t >> 3) & 63, f = t >> 9;
        int n = f >> 2, kk = f & 3;
        int k = kk * 32 + (l >> 4) * 8 + j;
        int col = n * 16 + (l & 15);
        WB1[t] = isf32 ? f2bf_raw(((const float*)W1p)[k * 128 + col])
                       : ((const unsigned short*)W1p)[k * 128 + col];
    } else if (t < T1 + T2) {
        int o = t - T1;
        int j = o & 7, l = (o >> 3) & 63, f = o >> 9;
        int n = f >> 2, kk = f & 3;
        int k = kk * 32 + (l >> 4) * 8 + j;
        int col = n * 16 + (l & 15);
        WB2[o] = isf32 ? f2bf_raw(((const float*)W2p)[k * 64 + col])
                       : ((const unsigned short*)W2p)[k * 64 + col];
    } else if (t < T1 + T2 + 128) {
        int o = t - T1 - T2;
        b1f[o] = isf32 ? ((const float*)b1p)[o] : bf2f_raw(((const unsigned short*)b1p)[o]);
    } else if (t < T1 + T2 + 192) {
        int o = t - T1 - T2 - 128;
        b2f[o] = isf32 ? ((const float*)b2p)[o] : bf2f_raw(((const unsigned short*)b2p)[o]);
    }
}

// ---------------- CSR build, bucket-granular ----------------
// 1) ms_count: per-block LDS bucket histogram -> global bucket totals.

__global__ __launch_bounds__(256) void ms_count_kernel(const int* __restrict__ dst,
                                                       int* __restrict__ bktcnt,
                                                       int E, int nbuk) {
    __shared__ int cnt[MAXBUK];
    const int t = threadIdx.x;
    const int e0 = blockIdx.x * 4096;
    const int e1 = min(E, e0 + 4096);
    for (int b = t; b < nbuk; b += 256) cnt[b] = 0;
    __syncthreads();
    for (int e = e0 + t; e < e1; e += 256) atomicAdd(&cnt[dst[e] >> 8], 1);
    __syncthreads();
    for (int b = t; b < nbuk; b += 256) {
        int c = cnt[b];
        if (c) atomicAdd(&bktcnt[b], c);
    }
}

// 2) bscan: exclusive scan of bucket totals -> bofs/bcur; rofs[n]=E.
__global__ __launch_bounds__(1024) void bscan_kernel(const int* __restrict__ bktcnt,
                                                     int* __restrict__ bofs,
                                                     int* __restrict__ bcur,
                                                     int* __restrict__ rofs,
                                                     int nbuk, int n, int total) {
    __shared__ int ps[1024];
    const int t = threadIdx.x;
    int v = (t < nbuk) ? bktcnt[t] : 0;
    ps[t] = v;
    __syncthreads();
    for (int o = 1; o < 1024; o <<= 1) {
        int u = (t >= o) ? ps[t - o] : 0;
        __syncthreads();
        ps[t] += u;
        __syncthreads();
    }
    if (t < nbuk) {
        int ex = ps[t] - v;
        bofs[t] = ex;
        bcur[t] = ex;
    }
    if (t == 0) {
        bofs[nbuk] = total;
        rofs[n] = total;
    }
}

// 3) ms_scatter: bin edges into per-bucket contiguous chunks (packed = (dst&255)<<24 | src).
__global__ __launch_bounds__(256) void ms_scatter_kernel(const int* __restrict__ src,
                                                         const int* __restrict__ dst,
                                                         int* __restrict__ bcur,
                                                         unsigned* __restrict__ packed,
                                                         int E, int nbuk) {
    __shared__ int cnt[MAXBUK];
    __shared__ int gbase[MAXBUK];
    const int t = threadIdx.x;
    const int e0 = blockIdx.x * 4096;
    const int e1 = min(E, e0 + 4096);
    for (int b = t; b < nbuk; b += 256) cnt[b] = 0;
    __syncthreads();
    for (int e = e0 + t; e < e1; e += 256) atomicAdd(&cnt[dst[e] >> 8], 1);
    __syncthreads();
    for (int b = t; b < nbuk; b += 256) {
        int c = cnt[b];
        gbase[b] = c ? atomicAdd(&bcur[b], c) : 0;
        cnt[b] = 0;
    }
    __syncthreads();
    for (int e = e0 + t; e < e1; e += 256) {
        int d = dst[e];
        int b = d >> 8;
        int r = atomicAdd(&cnt[b], 1);
        packed[gbase[b] + r] = ((unsigned)(d & 255) << 24) | (unsigned)src[e];
    }
}

// 4) csr_fine2: one block per bucket. Local histogram -> per-node rofs/dinv; place edges.
__global__ __launch_bounds__(256) void csr_fine2_kernel(const unsigned* __restrict__ packed,
                                                        const int* __restrict__ bofs,
                                                        int* __restrict__ rofs,
                                                        float* __restrict__ dinv,
                                                        int* __restrict__ csrc, int n) {
    __shared__ int cnt2[NPB];
    __shared__ int cur[NPB];
    const int t = threadIdx.x;
    const int b = blockIdx.x;
    const int node0 = b << 8;
    const int nn = min(NPB, n - node0);
    cnt2[t] = 0;
    __syncthreads();
    const int beg = bofs[b], end = bofs[b + 1];
    for (int i = beg + t; i < end; i += 256) atomicAdd(&cnt2[packed[i] >> 24], 1);
    __syncthreads();
    int c = cnt2[t];
    cur[t] = c;
    __syncthreads();
    for (int o = 1; o < 256; o <<= 1) {        // inclusive scan over 256 local counts
        int u = (t >= o) ? cur[t - o] : 0;
        __syncthreads();
        cur[t] += u;
        __syncthreads();
    }
    const int base = beg + cur[t] - c;          // exclusive
    if (t < nn) {
        rofs[node0 + t] = base;
        dinv[node0 + t] = rsqrtf((float)(c + 1));
    }
    __syncthreads();
    cur[t] = base;
    __syncthreads();
    for (int i = beg + t; i < end; i += 256) {
        unsigned u = packed[i];
        int pos = atomicAdd(&cur[u >> 24], 1);
        csrc[pos] = (int)(u & 0xFFFFFFu);
    }
}

// ---------------- GEMM1 (MFMA): H[nrows x 128] = X * W1, bf16 out (runtime dtype) ----------------

__global__ __launch_bounds__(256) void gemm1_mfma(const void* __restrict__ Xp,
                                                  const unsigned short* __restrict__ WB1,
                                                  unsigned short* __restrict__ H, int nrows,
                                                  const int* __restrict__ flag) {
    __shared__ __align__(16) unsigned short Xs[128 * 136];
    __shared__ __align__(16) unsigned short Cs[128 * 68];
    const int t = threadIdx.x;
    const int r0 = blockIdx.x * 128;
    const int isf32 = *flag;

    if (isf32) {
        const float4* Xg = (const float4*)Xp;
        #pragma unroll
        for (int i = 0; i < 16; ++i) {
            int idx = t + 256 * i;
            int row = idx >> 5, c4 = idx & 31;
            float4 v = {0.f, 0.f, 0.f, 0.f};
            if (r0 + row < nrows) v = Xg[(size_t)(r0 + row) * 32 + c4];
            unsigned lo = (unsigned)f2bf_raw(v.x) | ((unsigned)f2bf_raw(v.y) << 16);
            unsigned hi = (unsigned)f2bf_raw(v.z) | ((unsigned)f2bf_raw(v.w) << 16);
            *reinterpret_cast<uint2*>(&Xs[row * 136 + c4 * 4]) = make_uint2(lo, hi);
        }
    } else {
        const uint4* Xg = (const uint4*)Xp;
        #pragma unroll
        for (int i = 0; i < 8; ++i) {
            int idx = t + 256 * i;
            int row = idx >> 4, c8 = idx & 15;
            uint4 v = {0u, 0u, 0u, 0u};
            if (r0 + row < nrows) v = Xg[(size_t)(r0 + row) * 16 + c8];
            *reinterpret_cast<uint4*>(&Xs[row * 136 + c8 * 8]) = v;
        }
    }
    __syncthreads();

    const int lane = t & 63, w = t >> 6;
    const int m0 = w * 32;
    short8 a[2][4];
    #pragma unroll
    for (int rt = 0; rt < 2; ++rt)
        #pragma unroll
        for (int kk = 0; kk < 4; ++kk)
            a[rt][kk] = *reinterpret_cast<const short8*>(
                &Xs[(m0 + rt * 16 + (lane & 15)) * 136 + kk * 32 + (lane >> 4) * 8]);

    for (int p = 0; p < 2; ++p) {
        short8 b[4][4];
        #pragma unroll
        for (int n = 0; n < 4; ++n)
            #pragma unroll
            for (int kk = 0; kk < 4; ++kk)
                b[n][kk] = *reinterpret_cast<const short8*>(
                    WB1 + (size_t)(((p * 4 + n) * 4 + kk) * 64 + lane) * 8);
        f32x4 acc[2][4];
        #pragma unroll
        for (int rt = 0; rt < 2; ++rt)
            #pragma unroll
            for (int n = 0; n < 4; ++n) {
                acc[rt][n] = (f32x4){0.f, 0.f, 0.f, 0.f};
                #pragma unroll
                for (int kk = 0; kk < 4; ++kk)
                    acc[rt][n] = __builtin_amdgcn_mfma_f32_16x16x32_bf16(
                        a[rt][kk], b[n][kk], acc[rt][n], 0, 0, 0);
            }
        if (p) __syncthreads();
        #pragma unroll
        for (int rt = 0; rt < 2; ++rt)
            #pragma unroll
            for (int n = 0; n < 4; ++n)
                #pragma unroll
                for (int r = 0; r < 4; ++r) {
                    int row = m0 + rt * 16 + (lane >> 4) * 4 + r;
                    Cs[row * 68 + n * 16 + (lane & 15)] = f2bf_raw(acc[rt][n][r]);
                }
        __syncthreads();
        #pragma unroll
        for (int i = 0; i < 8; ++i) {
            int idx = t + 256 * i;
            int row = idx >> 4, c4 = idx & 15;
            if (r0 + row < nrows) {
                uint2 v = *reinterpret_cast<const uint2*>(&Cs[row * 68 + c4 * 4]);
                *reinterpret_cast<uint2*>(H + (size_t)(r0 + row) * 128 + p * 64 + c4 * 4) = v;
            }
        }
        if (!p) __syncthreads();
    }
}

// ---------------- Aggregation, wave-per-node, 4 outstanding gathers (round-7 proven) ----------------

template <bool RELU_BIAS>
__global__ __launch_bounds__(256) void agg128_v2(const unsigned* __restrict__ H32,
                                                 const int* __restrict__ rofs,
                                                 const int* __restrict__ csrc,
                                                 const float* __restrict__ dinv,
                                                 const float* __restrict__ biasf,
                                                 unsigned* __restrict__ G32, int n) {
    const int lane = threadIdx.x & 63;
    const int node = blockIdx.x * 4 + (threadIdx.x >> 6);
    if (node >= n) return;
    const float di = dinv[node];
    unsigned u = H32[(size_t)node * 64 + lane];
    const float dii = di * di;
    float a0 = dii * lo_f(u), a1 = dii * hi_f(u);
    int j = rofs[node];
    const int end = rofs[node + 1];
    for (; j + 3 < end; j += 4) {
        int s0 = csrc[j], s1 = csrc[j + 1], s2 = csrc[j + 2], s3 = csrc[j + 3];
        float w0 = di * dinv[s0], w1 = di * dinv[s1];
        float w2 = di * dinv[s2], w3 = di * dinv[s3];
        unsigned v0 = H32[(size_t)s0 * 64 + lane];
        unsigned v1 = H32[(size_t)s1 * 64 + lane];
        unsigned v2 = H32[(size_t)s2 * 64 + lane];
        unsigned v3 = H32[(size_t)s3 * 64 + lane];
        a0 = fmaf(w0, lo_f(v0), a0); a1 = fmaf(w0, hi_f(v0), a1);
        a0 = fmaf(w1, lo_f(v1), a0); a1 = fmaf(w1, hi_f(v1), a1);
        a0 = fmaf(w2, lo_f(v2), a0); a1 = fmaf(w2, hi_f(v2), a1);
        a0 = fmaf(w3, lo_f(v3), a0); a1 = fmaf(w3, hi_f(v3), a1);
    }
    for (; j < end; ++j) {
        int s = csrc[j];
        float w = di * dinv[s];
        unsigned v = H32[(size_t)s * 64 + lane];
        a0 = fmaf(w, lo_f(v), a0);
        a1 = fmaf(w, hi_f(v), a1);
    }
    if (RELU_BIAS) {
        a0 = fmaxf(a0 + biasf[2 * lane], 0.f);
        a1 = fmaxf(a1 + biasf[2 * lane + 1], 0.f);
    }
    G32[(size_t)node * 64 + lane] = (unsigned)f2bf_raw(a0) | ((unsigned)f2bf_raw(a1) << 16);
}

// ---------------- GEMM2 (MFMA) + bias + log_softmax (runtime output dtype) ----------------

__global__ __launch_bounds__(256) void gemm2_mfma(const unsigned short* __restrict__ X,
                                                  const unsigned short* __restrict__ WB2,
                                                  const float* __restrict__ b2f,
                                                  void* __restrict__ OUTv, int nrows,
                                                  const int* __restrict__ flag) {
    __shared__ __align__(16) unsigned short Xs[128 * 136];
    const int t = threadIdx.x;
    const int r0 = blockIdx.x * 128;
    const int outf32 = *flag;

    const uint4* Xg = (const uint4*)X;
    #pragma unroll
    for (int i = 0; i < 8; ++i) {
        int idx = t + 256 * i;
        int row = idx >> 4, c8 = idx & 15;
        uint4 v = {0u, 0u, 0u, 0u};
        if (r0 + row < nrows) v = Xg[(size_t)(r0 + row) * 16 + c8];
        *reinterpret_cast<uint4*>(&Xs[row * 136 + c8 * 8]) = v;
    }
    __syncthreads();

    const int lane = t & 63, w = t >> 6;
    const int m0 = w * 32;
    short8 a[2][4];
    #pragma unroll
    for (int rt = 0; rt < 2; ++rt)
        #pragma unroll
        for (int kk = 0; kk < 4; ++kk)
            a[rt][kk] = *reinterpret_cast<const short8*>(
                &Xs[(m0 + rt * 16 + (lane & 15)) * 136 + kk * 32 + (lane >> 4) * 8]);

    short8 b[4][4];
    #pragma unroll
    for (int n = 0; n < 4; ++n)
        #pragma unroll
        for (int kk = 0; kk < 4; ++kk)
            b[n][kk] = *reinterpret_cast<const short8*>(
                WB2 + (size_t)((n * 4 + kk) * 64 + lane) * 8);

    f32x4 acc[2][4];
    #pragma unroll
    for (int rt = 0; rt < 2; ++rt)
        #pragma unroll
        for (int n = 0; n < 4; ++n) {
            acc[rt][n] = (f32x4){0.f, 0.f, 0.f, 0.f};
            #pragma unroll
            for (int kk = 0; kk < 4; ++kk)
                acc[rt][n] = __builtin_amdgcn_mfma_f32_16x16x32_bf16(
                    a[rt][kk], b[n][kk], acc[rt][n], 0, 0, 0);
        }

    float bc[4];
    #pragma unroll
    for (int n = 0; n < 4; ++n) bc[n] = b2f[n * 16 + (lane & 15)];
    #pragma unroll
    for (int rt = 0; rt < 2; ++rt)
        #pragma unroll
        for (int n = 0; n < 4; ++n)
            #pragma unroll
            for (int r = 0; r < 4; ++r) acc[rt][n][r] += bc[n];

    float lse[2][4];
    #pragma unroll
    for (int rt = 0; rt < 2; ++rt)
        #pragma unroll
        for (int r = 0; r < 4; ++r) {
            float m = fmaxf(fmaxf(acc[rt][0][r], acc[rt][1][r]),
                            fmaxf(acc[rt][2][r], acc[rt][3][r]));
            #pragma unroll
            for (int o = 1; o < 16; o <<= 1) m = fmaxf(m, __shfl_xor(m, o, 64));
            float s = __expf(acc[rt][0][r] - m) + __expf(acc[rt][1][r] - m) +
                      __expf(acc[rt][2][r] - m) + __expf(acc[rt][3][r] - m);
            #pragma unroll
            for (int o = 1; o < 16; o <<= 1) s += __shfl_xor(s, o, 64);
            lse[rt][r] = m + __logf(s);
        }

    const int colb = lane & 15, q = lane >> 4;
    #pragma unroll
    for (int rt = 0; rt < 2; ++rt)
        #pragma unroll
        for (int r = 0; r < 4; ++r) {
            int grow = r0 + m0 + rt * 16 + q * 4 + r;
            if (grow < nrows) {
                if (outf32) {
                    float* Of = (float*)OUTv;
                    #pragma unroll
                    for (int n = 0; n < 4; ++n)
                        Of[(size_t)grow * 64 + n * 16 + colb] = acc[rt][n][r] - lse[rt][r];
                } else {
                    unsigned short* Ob = (unsigned short*)OUTv;
                    #pragma unroll
                    for (int n = 0; n < 4; ++n)
                        Ob[(size_t)grow * 64 + n * 16 + colb] = f2bf_raw(acc[rt][n][r] - lse[rt][r]);
                }
            }
        }
}

// ---------------- launch ----------------

extern "C" void kernel_launch(void* const* d_in, const int* in_sizes, int n_in,
                              void* d_out, int out_size, void* d_ws, size_t ws_size,
                              hipStream_t stream) {
    const void* x  = d_in[0];
    const int*  ei = (const int*)d_in[1];
    const void* W1 = d_in[2];
    const void* b1 = d_in[3];
    const void* W2 = d_in[4];
    const void* b2 = d_in[5];

    const int N = in_sizes[0] / 128;
    const int E = in_sizes[1] / 2;
    const int* src = ei;
    const int* dst = ei + E;
    const int NBUK = (N + NPB - 1) / NPB;     // 391 for N=100K

    char* p = (char*)d_ws;
    auto alloc = [&](size_t bytes) { char* q = p; p += (bytes + 255) & ~255ull; return q; };
    int*   flag   = (int*)  alloc(4);
    int*   rofs   = (int*)  alloc((size_t)(N + 1) * 4);
    float* dinv   = (float*)alloc((size_t)N * 4);
    int*   bktcnt = (int*)  alloc((size_t)NBUK * 4);
    int*   bofs   = (int*)  alloc((size_t)(NBUK + 1) * 4);
    int*   bcur   = (int*)  alloc((size_t)NBUK * 4);
    float* b1f    = (float*)alloc(128 * 4);
    float* b2f    = (float*)alloc(64 * 4);
    unsigned short* WB1 = (unsigned short*)alloc(16384 * 2);
    unsigned short* WB2 = (unsigned short*)alloc(8192 * 2);
    unsigned* big = (unsigned*)alloc((size_t)N * 128 * 2);   // h1, later a2 (row-major)
    unsigned* packed = (unsigned*)d_out;          // 6.4 MB scratch in d_out
    int*      csrc   = (int*)d_out + E;           // 6.4 MB scratch in d_out
    unsigned* g1 = (unsigned*)d_in[0];            // g1 into x's buffer (x dead after gemm1)
    (void)ws_size; (void)n_in; (void)out_size;

    hipMemsetAsync(bktcnt, 0, (size_t)NBUK * 4, stream);
    sniff_kernel<<<1, 1024, 0, stream>>>((const unsigned short*)W1, in_sizes[2], flag);
    prep_kernel<<<97, 256, 0, stream>>>(W1, W2, b1, b2, WB1, WB2, b1f, b2f, flag);
    const int MSB = (E + 4095) / 4096;
    ms_count_kernel<<<MSB, 256, 0, stream>>>(dst, bktcnt, E, NBUK);
    bscan_kernel<<<1, 1024, 0, stream>>>(bktcnt, bofs, bcur, rofs, NBUK, N, E);
    ms_scatter_kernel<<<MSB, 256, 0, stream>>>(src, dst, bcur, packed, E, NBUK);
    csr_fine2_kernel<<<NBUK, 256, 0, stream>>>(packed, bofs, rofs, dinv, csrc, N);

    const int GB = (N + 127) / 128;
    gemm1_mfma<<<GB, 256, 0, stream>>>(x, WB1, (unsigned short*)big, N, flag);
    agg128_v2<true><<<(N + 3) / 4, 256, 0, stream>>>(big, rofs, csrc, dinv, b1f, g1, N);
    agg128_v2<false><<<(N + 3) / 4, 256, 0, stream>>>(g1, rofs, csrc, dinv, nullptr, big, N);
    gemm2_mfma<<<GB, 256, 0, stream>>>((const unsigned short*)big, WB2, b2f, d_out, N, flag);
}